// Round 5
// baseline (937.373 us; speedup 1.0000x reference)
//
#include <hip/hip_runtime.h>

// Problem constants
constexpr int Cc   = 256;               // channels
constexpr int Kc   = 1024;              // codebook size
constexpr int NT   = 128;               // rows per main block
constexpr int KTT  = 128;               // codes per k-tile
constexpr int CB   = 32;                // c-chunk per staged phase
constexpr int NLOC = 16 * 56 * 56;      // 50176
constexpr int NB   = 2;
constexpr int NTILES = NLOC / NT;       // 392
constexpr int NTOT = NB * NLOC;         // 100352
constexpr long long ZQV = (long long)NB * Cc * NLOC;
constexpr int MAIN_BLOCKS = NB * NTILES; // 784

// f32 square with a compiler barrier: numpy rounds x*x BEFORE summing;
// block -ffp-contract from fusing square into the following add.
__device__ __forceinline__ float sqf(float x) {
    float s = x * x;
    asm("" : "+v"(s));
    return s;
}

// numpy pairwise sum of squares, n=256 (two 128-halves, 8 accumulators
// stride-8, tree combine) — exact numpy reduction order.
template <typename Loader>
__device__ __forceinline__ float pw256_sq(Loader ld)
{
    float half[2];
    #pragma unroll
    for (int h = 0; h < 2; ++h) {
        float r[8];
        #pragma unroll
        for (int j = 0; j < 8; ++j) r[j] = sqf(ld(h * 128 + j));
        #pragma unroll
        for (int i = 8; i < 128; i += 8)
            #pragma unroll
            for (int j = 0; j < 8; ++j) r[j] += sqf(ld(h * 128 + i + j));
        half[h] = ((r[0] + r[1]) + (r[2] + r[3])) + ((r[4] + r[5]) + (r[6] + r[7]));
    }
    return half[0] + half[1];
}

__global__ void esq_pw(const float* __restrict__ key, float* __restrict__ esq)
{
    int k = blockIdx.x * 256 + threadIdx.x;
    if (k < Kc) {
        const float* a = key + (size_t)k * Cc;
        esq[k] = pw256_sq([&](int c) { return a[c]; });
    }
}

__global__ void zsq_pw(const float* __restrict__ z, float* __restrict__ zsq)
{
    int p = blockIdx.x * 256 + threadIdx.x;
    int b = p / NLOC, loc = p - b * NLOC;
    const float* a = z + (size_t)b * Cc * NLOC + loc;
    zsq[p] = pw256_sq([&](int c) { return a[(size_t)c * NLOC]; });
}

// Granule swizzle: 16B-granule g (0..31) of a 128-float LDS row stored at
// physical granule g ^ (g>>3). Bijective; makes the 16-address stride-32B
// 8-float reads hit each bank-group exactly 2x (2-way = free).
__device__ __forceinline__ int sgr(int g) { return g ^ (g >> 3); }

// ---------------------------------------------------------------------------
// Main kernel: numpy-exact f32 distances + first-occurrence argmin.
// 128x128 tile, 8x8 register tile/thread, CB=32 c-chunks, swizzled LDS.
// ---------------------------------------------------------------------------
__global__ __launch_bounds__(256, 4)
void vq_main(const float* __restrict__ z, const float* __restrict__ key,
             const float* __restrict__ val, const float* __restrict__ esq,
             const float* __restrict__ zsq,
             float* __restrict__ out, double* __restrict__ partial)
{
    __shared__ __align__(16) float zt[CB * 128];   // 16 KB  [c][n-swizzled]
    __shared__ __align__(16) float et[CB * 128];   // 16 KB  [c][k-swizzled]
    __shared__ int    idx_sh[NT];
    __shared__ double wred[4];

    const int tid = threadIdx.x;
    const int l   = tid & 63;
    const int w   = tid >> 6;
    const int blk = blockIdx.x;
    const int b   = blk / NTILES;
    const int n0  = (blk % NTILES) * NT;
    const float* zb = z + (size_t)b * Cc * NLOC;

    const int col = tid & 15;        // code group (8 codes)
    const int row = tid >> 4;        // row group (8 rows)

    const int zoff0 = sgr(2 * row) * 4,     zoff1 = sgr(2 * row + 1) * 4;
    const int eoff0 = sgr(2 * col) * 4,     eoff1 = sgr(2 * col + 1) * 4;

    float zsq_r[8];
    #pragma unroll
    for (int a = 0; a < 8; ++a)
        zsq_r[a] = zsq[b * NLOC + n0 + row * 8 + a];

    float bestv[8];
    int   besti[8];
    #pragma unroll
    for (int a = 0; a < 8; ++a) { bestv[a] = 3.4e38f; besti[a] = 0; }

    for (int kt = 0; kt < Kc; kt += KTT) {
        float acc[8][8];
        #pragma unroll
        for (int a = 0; a < 8; ++a)
            #pragma unroll
            for (int q = 0; q < 8; ++q) acc[a][q] = 0.0f;

        for (int cc0 = 0; cc0 < Cc; cc0 += CB) {
            __syncthreads();   // previous phase fully consumed

            // --- zt stage: 32 c-rows x 32 granules, coalesced 512B global
            //     reads, bijective swizzled b128 LDS writes (optimal) ---
            {
                int g  = l & 31;
                int pg = sgr(g);
                #pragma unroll
                for (int it = 0; it < 4; ++it) {
                    int c = (l >> 5) + (w << 1) + (it << 3);     // 0..31
                    float4 v = *reinterpret_cast<const float4*>(
                        zb + (size_t)(cc0 + c) * NLOC + n0 + 4 * g);
                    *reinterpret_cast<float4*>(&zt[c * 128 + pg * 4]) = v;
                }
            }
            // --- et stage: 128 codes x 32 c, transposed into [c][k-swz] ---
            {
                int kk = (l >> 2) | (w << 4);                    // 0..63
                #pragma unroll
                for (int itk = 0; itk < 2; ++itk) {
                    int k   = kk | (itk << 6);                   // 0..127
                    int pgk = sgr(k >> 2) * 4 + (k & 3);         // phys float pos
                    #pragma unroll
                    for (int itc = 0; itc < 2; ++itc) {
                        int gc = (l & 3) | (itc << 2);           // 0..7
                        float4 v = *reinterpret_cast<const float4*>(
                            key + (size_t)(kt + k) * Cc + cc0 + 4 * gc);
                        et[(4 * gc + 0) * 128 + pgk] = v.x;
                        et[(4 * gc + 1) * 128 + pgk] = v.y;
                        et[(4 * gc + 2) * 128 + pgk] = v.z;
                        et[(4 * gc + 3) * 128 + pgk] = v.w;
                    }
                }
            }
            __syncthreads();

            // --- compute: ascending c, sequential fmaf chain per (row,code) ---
            for (int c = 0; c < CB; ++c) {
                const float* zr = &zt[c * 128];
                const float* er = &et[c * 128];
                float4 z0 = *reinterpret_cast<const float4*>(zr + zoff0);
                float4 z1 = *reinterpret_cast<const float4*>(zr + zoff1);
                float4 e0 = *reinterpret_cast<const float4*>(er + eoff0);
                float4 e1 = *reinterpret_cast<const float4*>(er + eoff1);
                float za[8] = {z0.x, z0.y, z0.z, z0.w, z1.x, z1.y, z1.z, z1.w};
                float ea[8] = {e0.x, e0.y, e0.z, e0.w, e1.x, e1.y, e1.z, e1.w};
                #pragma unroll
                for (int a = 0; a < 8; ++a)
                    #pragma unroll
                    for (int q = 0; q < 8; ++q)
                        acc[a][q] = fmaf(za[a], ea[q], acc[a][q]);
            }
        }

        // d = f32( f32(zsq + esq) - 2*m ), ascending k within thread
        #pragma unroll
        for (int q = 0; q < 8; ++q) {
            int kg = kt + col * 8 + q;
            float e2 = esq[kg];
            #pragma unroll
            for (int a = 0; a < 8; ++a) {
                float t = zsq_r[a] + e2;
                float d = fmaf(-2.0f, acc[a][q], t);
                if (d < bestv[a]) { bestv[a] = d; besti[a] = kg; }
            }
        }
    }

    __syncthreads();   // tiles dead -> alias for argmin reduction
    float (*redv_s)[16] = reinterpret_cast<float (*)[16]>(zt);  // 8 KB
    int   (*redi_s)[16] = reinterpret_cast<int   (*)[16]>(et);  // 8 KB

    #pragma unroll
    for (int a = 0; a < 8; ++a) {
        redv_s[row * 8 + a][col] = bestv[a];
        redi_s[row * 8 + a][col] = besti[a];
    }
    __syncthreads();

    if (tid < NT) {
        float bv = redv_s[tid][0];
        int   bi = redi_s[tid][0];
        for (int t = 1; t < 16; ++t) {
            float v = redv_s[tid][t];
            int  ii = redi_s[tid][t];
            if (v < bv || (v == bv && ii < bi)) { bv = v; bi = ii; }  // first occurrence
        }
        idx_sh[tid] = bi;
        out[ZQV + (long long)b * NLOC + n0 + tid] = (float)bi;
    }
    __syncthreads();

    // gather z_q_value (bit-exact copies) + f64 loss (z re-read from global)
    double lacc = 0.0;
    for (int i = tid; i < Cc * NT; i += 256) {
        int c = i >> 7, n = i & (NT - 1);
        int id = idx_sh[n];
        out[((size_t)b * Cc + c) * NLOC + n0 + n] = val[(size_t)id * Cc + c];
        double diff = (double)key[(size_t)id * Cc + c]
                    - (double)zb[(size_t)c * NLOC + n0 + n];
        lacc = fma(diff, diff, lacc);
    }
    for (int off = 32; off > 0; off >>= 1) lacc += __shfl_down(lacc, off);
    if ((tid & 63) == 0) wred[tid >> 6] = lacc;
    __syncthreads();
    if (tid == 0) partial[blk] = wred[0] + wred[1] + wred[2] + wred[3];
}

__global__ void fin_kernel(const double* __restrict__ partial, float* __restrict__ out_loss)
{
    __shared__ double sh[256];
    double s = 0.0;
    for (int i = threadIdx.x; i < MAIN_BLOCKS; i += 256) s += partial[i];
    sh[threadIdx.x] = s;
    __syncthreads();
    for (int st = 128; st > 0; st >>= 1) {
        if (threadIdx.x < st) sh[threadIdx.x] += sh[threadIdx.x + st];
        __syncthreads();
    }
    if (threadIdx.x == 0)
        out_loss[0] = (float)(1.25 * sh[0] / (double)((long long)NTOT * Cc));
}

// ---------------------------------------------------------------------------
extern "C" void kernel_launch(void* const* d_in, const int* in_sizes, int n_in,
                              void* d_out, int out_size, void* d_ws, size_t ws_size,
                              hipStream_t stream)
{
    const float* z   = (const float*)d_in[0];
    const float* key = (const float*)d_in[1];
    const float* val = (const float*)d_in[2];
    float* out = (float*)d_out;

    double* partial = (double*)d_ws;                   // 784 f64
    float*  esq     = (float*)(partial + MAIN_BLOCKS); // 1024 f32
    float*  zsq     = esq + Kc;                        // 100352 f32

    hipLaunchKernelGGL(esq_pw, dim3((Kc + 255) / 256), dim3(256), 0, stream, key, esq);
    hipLaunchKernelGGL(zsq_pw, dim3(NTOT / 256), dim3(256), 0, stream, z, zsq);
    hipLaunchKernelGGL(vq_main, dim3(MAIN_BLOCKS), dim3(256), 0, stream,
                       z, key, val, esq, zsq, out, partial);
    hipLaunchKernelGGL(fin_kernel, dim3(1), dim3(256), 0, stream, partial, out + ZQV + NTOT);
}